// Round 6
// baseline (641.251 us; speedup 1.0000x reference)
//
#include <hip/hip_runtime.h>
#include <cstdint>

typedef unsigned short u16;
typedef unsigned int u32;
typedef __attribute__((ext_vector_type(4))) float f32x4;
typedef __attribute__((ext_vector_type(8))) __bf16 bf16x8;
typedef __attribute__((ext_vector_type(8))) unsigned short u16x8;
typedef __attribute__((ext_vector_type(4))) unsigned int u32x4;

#define S_LEN 2048
#define BATCH 2
#define NQH 32
#define NKVH 8
#define HD 96
#define EMB 3072
#define QKVN 4608
#define KOFF 3072
#define VOFF 3840
#define KSP 104

__device__ __forceinline__ u16 f2b(float f) {
    u32 u = __float_as_uint(f);
    u32 r = (u + 0x7fffu + ((u >> 16) & 1u)) >> 16;
    return (u16)r;
}
__device__ __forceinline__ float b2f(u16 h) { return __uint_as_float(((u32)h) << 16); }
__device__ __forceinline__ u32 cvtpk(float lo, float hi) {
    u32 r;
    asm("v_cvt_pk_bf16_f32 %0, %1, %2" : "=v"(r) : "v"(lo), "v"(hi));
    return r;
}

// ---------------- fp32 -> bf16 bulk convert ----------------
__global__ __launch_bounds__(256) void conv_f2b(const float* __restrict__ in,
                                                u16* __restrict__ outp, int n8) {
    const int i = blockIdx.x * 256 + threadIdx.x;
    if (i >= n8) return;
    const f32x4* q = (const f32x4*)(in + (size_t)i * 8);
    const f32x4 a = q[0], b = q[1];
    u16x8 t;
#pragma unroll
    for (int j = 0; j < 4; ++j) {
        t[j] = f2b(a[j]);
        t[j + 4] = f2b(b[j]);
    }
    *(u16x8*)(outp + (size_t)i * 8) = t;
}

// ---------------- async global->LDS helper ----------------
typedef __attribute__((address_space(1))) const uint32_t gas_u32;
typedef __attribute__((address_space(3))) uint32_t las_u32;
__device__ __forceinline__ void gld_lds16(const u16* g, u16* l) {
    __builtin_amdgcn_global_load_lds((gas_u32*)g, (las_u32*)l, 16, 0, 0);
}

#define WAITV2 asm volatile("s_waitcnt vmcnt(2)" ::: "memory")
#define LGKM0 asm volatile("s_waitcnt lgkmcnt(0)" ::: "memory")
#define BARRIER __builtin_amdgcn_s_barrier()
#define SCHEDB __builtin_amdgcn_sched_barrier(0)

// ============ 256x256 8-phase GEMM (m201 template, re-derived schedule) ============
// C[M,N] = A[M,K]*B[N,K]^T. 512 thr = 8 waves (2M x 4N), BK=64, LDS 128KB dbuf.
// Even K-tiles in buf0, odd in buf1. Per phase: 16 MFMA quadrant + 1 half-tile stage.
// st_16x32 swizzle: seg ^= ((row>>2)&1)<<1, applied to GLOBAL source (gld_lds writes
// linear) and to ds_read addr (same involution). vmcnt(2) only at P4/P8 end.
__device__ __forceinline__ void stage_half(const u16* __restrict__ Gp, int ldg, int k0,
                                           u16* lds_op, int h, int tid) {
#pragma unroll
    for (int L = 0; L < 2; ++L) {
        const int c = L * 512 + tid;
        const int r = c >> 3;
        const int seg = (c & 7) ^ (((r >> 2) & 1) << 1);
        const u16* src = Gp + (size_t)(h * 128 + r) * ldg + k0 + seg * 8;
        u16* dst = lds_op + h * 8192 + (L * 512 + (tid & 448)) * 8;
        gld_lds16(src, dst);
    }
}

__device__ __forceinline__ bf16x8 frag(const u16* opb, int row, int segl) {
    const int seg = segl ^ (((row >> 2) & 1) << 1);
    return *(const bf16x8*)(opb + row * 64 + seg * 8);
}

template <bool OUTF32>
__global__ __launch_bounds__(512, 2) void gemm_bt8(const u16* __restrict__ Ap,
                                                   const u16* __restrict__ Bp,
                                                   void* __restrict__ Cp,
                                                   int M, int N, int K, int ldc) {
    __shared__ __align__(16) u16 S[65536];  // 128 KB: bufA0|bufB0|bufA1|bufB1 (16384 ea)
    const int tid = threadIdx.x;
    const int lane = tid & 63;
    const int lrow = lane & 15, lhi = lane >> 4;
    const int wid = tid >> 6;
    const int wr = wid >> 2, wc = wid & 3;
    const int bm = blockIdx.y * 256, bn = blockIdx.x * 256;
    const u16* Ab = Ap + (size_t)bm * K;
    const u16* Bb = Bp + (size_t)bn * K;
    u16* const AE = S;              // even-tile A
    u16* const BE = S + 16384;      // even-tile B
    u16* const AO = S + 32768;      // odd-tile A
    u16* const BO = S + 49152;      // odd-tile B

    f32x4 acc[8][4] = {};
    const int nt = K >> 6;  // even (K=3072 -> 48)
    const int arow0 = wr * 128 + lrow;
    const int brow0 = wc * 64 + lrow;

    // prologue: tile0 full + A0(tile1); leave A0(1) in flight
    stage_half(Ab, K, 0, AE, 0, tid);
    stage_half(Ab, K, 0, AE, 1, tid);
    stage_half(Bb, K, 0, BE, 0, tid);
    stage_half(Bb, K, 0, BE, 1, tid);
    stage_half(Ab, K, 64, AO, 0, tid);
    WAITV2;
    BARRIER;

    bf16x8 af[4][2], bfr[2][2];
    for (int j = 0; j < (nt >> 1); ++j) {
        const int o = 2 * j + 1;
        const int ke2 = (2 * j + 2 < nt) ? (2 * j + 2) * 64 : 0;
        const int ko2 = (2 * j + 3 < nt) ? (2 * j + 3) * 64 : 0;

        // ---- P1: tile e quadrant (mi0-3, ni0-1); stage A1(o) ----
#pragma unroll
        for (int mi = 0; mi < 4; ++mi) {
            af[mi][0] = frag(AE, arow0 + mi * 16, lhi);
            af[mi][1] = frag(AE, arow0 + mi * 16, 4 + lhi);
        }
#pragma unroll
        for (int ni = 0; ni < 2; ++ni) {
            bfr[ni][0] = frag(BE, brow0 + ni * 16, lhi);
            bfr[ni][1] = frag(BE, brow0 + ni * 16, 4 + lhi);
        }
        stage_half(Ab, K, o * 64, AO, 1, tid);
        BARRIER;
        LGKM0;
        SCHEDB;
        __builtin_amdgcn_s_setprio(1);
#pragma unroll
        for (int mi = 0; mi < 4; ++mi)
#pragma unroll
            for (int ni = 0; ni < 2; ++ni)
#pragma unroll
                for (int kc = 0; kc < 2; ++kc)
                    acc[mi][ni] = __builtin_amdgcn_mfma_f32_16x16x32_bf16(
                        af[mi][kc], bfr[ni][kc], acc[mi][ni], 0, 0, 0);
        __builtin_amdgcn_s_setprio(0);
        BARRIER;

        // ---- P2: (mi0-3, ni2-3); stage B0(o) ----
#pragma unroll
        for (int ni = 0; ni < 2; ++ni) {
            bfr[ni][0] = frag(BE, brow0 + (ni + 2) * 16, lhi);
            bfr[ni][1] = frag(BE, brow0 + (ni + 2) * 16, 4 + lhi);
        }
        stage_half(Bb, K, o * 64, BO, 0, tid);
        BARRIER;
        LGKM0;
        SCHEDB;
        __builtin_amdgcn_s_setprio(1);
#pragma unroll
        for (int mi = 0; mi < 4; ++mi)
#pragma unroll
            for (int ni = 0; ni < 2; ++ni)
#pragma unroll
                for (int kc = 0; kc < 2; ++kc)
                    acc[mi][ni + 2] = __builtin_amdgcn_mfma_f32_16x16x32_bf16(
                        af[mi][kc], bfr[ni][kc], acc[mi][ni + 2], 0, 0, 0);
        __builtin_amdgcn_s_setprio(0);
        BARRIER;

        // ---- P3: (mi4-7, ni0-1); stage B1(o) ----
#pragma unroll
        for (int mi = 0; mi < 4; ++mi) {
            af[mi][0] = frag(AE, arow0 + (mi + 4) * 16, lhi);
            af[mi][1] = frag(AE, arow0 + (mi + 4) * 16, 4 + lhi);
        }
#pragma unroll
        for (int ni = 0; ni < 2; ++ni) {
            bfr[ni][0] = frag(BE, brow0 + ni * 16, lhi);
            bfr[ni][1] = frag(BE, brow0 + ni * 16, 4 + lhi);
        }
        stage_half(Bb, K, o * 64, BO, 1, tid);
        BARRIER;
        LGKM0;
        SCHEDB;
        __builtin_amdgcn_s_setprio(1);
#pragma unroll
        for (int mi = 0; mi < 4; ++mi)
#pragma unroll
            for (int ni = 0; ni < 2; ++ni)
#pragma unroll
                for (int kc = 0; kc < 2; ++kc)
                    acc[mi + 4][ni] = __builtin_amdgcn_mfma_f32_16x16x32_bf16(
                        af[mi][kc], bfr[ni][kc], acc[mi + 4][ni], 0, 0, 0);
        __builtin_amdgcn_s_setprio(0);
        BARRIER;

        // ---- P4: (mi4-7, ni2-3); stage A0(e+2); vmcnt(2) gate for P5 reads ----
#pragma unroll
        for (int ni = 0; ni < 2; ++ni) {
            bfr[ni][0] = frag(BE, brow0 + (ni + 2) * 16, lhi);
            bfr[ni][1] = frag(BE, brow0 + (ni + 2) * 16, 4 + lhi);
        }
        stage_half(Ab, K, ke2, AE, 0, tid);
        BARRIER;
        LGKM0;
        SCHEDB;
        __builtin_amdgcn_s_setprio(1);
#pragma unroll
        for (int mi = 0; mi < 4; ++mi)
#pragma unroll
            for (int ni = 0; ni < 2; ++ni)
#pragma unroll
                for (int kc = 0; kc < 2; ++kc)
                    acc[mi + 4][ni + 2] = __builtin_amdgcn_mfma_f32_16x16x32_bf16(
                        af[mi][kc], bfr[ni][kc], acc[mi + 4][ni + 2], 0, 0, 0);
        __builtin_amdgcn_s_setprio(0);
        WAITV2;
        BARRIER;

        // ---- P5: tile o quadrant (mi0-3, ni0-1); stage A1(e+2) ----
#pragma unroll
        for (int mi = 0; mi < 4; ++mi) {
            af[mi][0] = frag(AO, arow0 + mi * 16, lhi);
            af[mi][1] = frag(AO, arow0 + mi * 16, 4 + lhi);
        }
#pragma unroll
        for (int ni = 0; ni < 2; ++ni) {
            bfr[ni][0] = frag(BO, brow0 + ni * 16, lhi);
            bfr[ni][1] = frag(BO, brow0 + ni * 16, 4 + lhi);
        }
        stage_half(Ab, K, ke2, AE, 1, tid);
        BARRIER;
        LGKM0;
        SCHEDB;
        __builtin_amdgcn_s_setprio(1);
#pragma unroll
        for (int mi = 0; mi < 4; ++mi)
#pragma unroll
            for (int ni = 0; ni < 2; ++ni)
#pragma unroll
                for (int kc = 0; kc < 2; ++kc)
                    acc[mi][ni] = __builtin_amdgcn_mfma_f32_16x16x32_bf16(
                        af[mi][kc], bfr[ni][kc], acc[mi][ni], 0, 0, 0);
        __builtin_amdgcn_s_setprio(0);
        BARRIER;

        // ---- P6: (mi0-3, ni2-3); stage B0(e+2) ----
#pragma unroll
        for (int ni = 0; ni < 2; ++ni) {
            bfr[ni][0] = frag(BO, brow0 + (ni + 2) * 16, lhi);
            bfr[ni][1] = frag(BO, brow0 + (ni + 2) * 16, 4 + lhi);
        }
        stage_half(Bb, K, ke2, BE, 0, tid);
        BARRIER;
        LGKM0;
        SCHEDB;
        __builtin_amdgcn_s_setprio(1);
#pragma unroll
        for (int mi = 0; mi < 4; ++mi)
#pragma unroll
            for (int ni = 0; ni < 2; ++ni)
#pragma unroll
                for (int kc = 0; kc < 2; ++kc)
                    acc[mi][ni + 2] = __builtin_amdgcn_mfma_f32_16x16x32_bf16(
                        af[mi][kc], bfr[ni][kc], acc[mi][ni + 2], 0, 0, 0);
        __builtin_amdgcn_s_setprio(0);
        BARRIER;

        // ---- P7: (mi4-7, ni0-1); stage B1(e+2) ----
#pragma unroll
        for (int mi = 0; mi < 4; ++mi) {
            af[mi][0] = frag(AO, arow0 + (mi + 4) * 16, lhi);
            af[mi][1] = frag(AO, arow0 + (mi + 4) * 16, 4 + lhi);
        }
#pragma unroll
        for (int ni = 0; ni < 2; ++ni) {
            bfr[ni][0] = frag(BO, brow0 + ni * 16, lhi);
            bfr[ni][1] = frag(BO, brow0 + ni * 16, 4 + lhi);
        }
        stage_half(Bb, K, ke2, BE, 1, tid);
        BARRIER;
        LGKM0;
        SCHEDB;
        __builtin_amdgcn_s_setprio(1);
#pragma unroll
        for (int mi = 0; mi < 4; ++mi)
#pragma unroll
            for (int ni = 0; ni < 2; ++ni)
#pragma unroll
                for (int kc = 0; kc < 2; ++kc)
                    acc[mi + 4][ni] = __builtin_amdgcn_mfma_f32_16x16x32_bf16(
                        af[mi][kc], bfr[ni][kc], acc[mi + 4][ni], 0, 0, 0);
        __builtin_amdgcn_s_setprio(0);
        BARRIER;

        // ---- P8: (mi4-7, ni2-3); stage A0(o+2); vmcnt(2) gate for next P1 ----
#pragma unroll
        for (int ni = 0; ni < 2; ++ni) {
            bfr[ni][0] = frag(BO, brow0 + (ni + 2) * 16, lhi);
            bfr[ni][1] = frag(BO, brow0 + (ni + 2) * 16, 4 + lhi);
        }
        stage_half(Ab, K, ko2, AO, 0, tid);
        BARRIER;
        LGKM0;
        SCHEDB;
        __builtin_amdgcn_s_setprio(1);
#pragma unroll
        for (int mi = 0; mi < 4; ++mi)
#pragma unroll
            for (int ni = 0; ni < 2; ++ni)
#pragma unroll
                for (int kc = 0; kc < 2; ++kc)
                    acc[mi + 4][ni + 2] = __builtin_amdgcn_mfma_f32_16x16x32_bf16(
                        af[mi][kc], bfr[ni][kc], acc[mi + 4][ni + 2], 0, 0, 0);
        __builtin_amdgcn_s_setprio(0);
        WAITV2;
        BARRIER;
    }

    // epilogue: C/D layout col=lane&15, row=(lane>>4)*4+reg
    const int orow = bm + wr * 128 + lhi * 4;
    const int ocol = bn + wc * 64 + lrow;
#pragma unroll
    for (int mi = 0; mi < 8; ++mi)
#pragma unroll
        for (int ni = 0; ni < 4; ++ni)
#pragma unroll
            for (int r = 0; r < 4; ++r) {
                const size_t idx = (size_t)(orow + mi * 16 + r) * ldc + ocol + ni * 16;
                if constexpr (OUTF32)
                    ((float*)Cp)[idx] = acc[mi][ni][r];
                else
                    ((u16*)Cp)[idx] = f2b(acc[mi][ni][r]);
            }
}

// ---------------- RoPE in-place, vectorized: 8 pairs per thread ----------------
__global__ __launch_bounds__(256) void gqa_rope8(u16* __restrict__ qkv,
                                                 const int* __restrict__ positions) {
    const int i = blockIdx.x * 256 + threadIdx.x;
    const int pc = i % 6;
    int t = i / 6;
    const int head = t % (NQH + NKVH);
    const int bs = t / (NQH + NKVH);
    const int pos = positions[bs & (S_LEN - 1)];
    const size_t base = (size_t)bs * QKVN +
                        (head < NQH ? head * HD : KOFF + (head - NQH) * HD) + pc * 8;
    const u16x8 a = *(const u16x8*)(qkv + base);
    const u16x8 b = *(const u16x8*)(qkv + base + 48);
    u16x8 ra, rb;
#pragma unroll
    for (int jj = 0; jj < 8; ++jj) {
        const int pair = pc * 8 + jj;
        const float invf = __expf(-(float)(2 * pair) * (1.0f / 96.0f) * 9.210340371976184f);
        const float ang = (float)pos * invf;
        float sn, cs;
        __sincosf(ang, &sn, &cs);
        const float t1 = b2f(a[jj]), t2 = b2f(b[jj]);
        ra[jj] = f2b(t1 * cs - t2 * sn);
        rb[jj] = f2b(t2 * cs + t1 * sn);
    }
    *(u16x8*)(qkv + base) = ra;
    *(u16x8*)(qkv + base + 48) = rb;
}

// ---------------- Flash GQA v5 (unchanged from R5) ----------------
__global__ __launch_bounds__(256) void gqa_attn5(const u16* __restrict__ qkv,
                                                 u16* __restrict__ out) {
    __shared__ __align__(16) u16 Ks[64 * KSP];
    __shared__ __align__(16) u16 Vtmp[64 * 96];
    __shared__ __align__(16) u16 Vt[96 * 72];

    const int tid = threadIdx.x;
    const int wave = tid >> 6, lane = tid & 63;
    const int lrow = lane & 15, lhi = lane >> 4;
    const int bx = blockIdx.x;
    const int qt32 = 63 - (bx >> 4);
    const int kvh = (bx >> 1) & 7, bb = bx & 1;
    const int qh = kvh * 4 + wave;
    const int srow0 = bb * S_LEN + qt32 * 32;
    const int kb_last = (qt32 * 32 + 31) >> 6;
    const float cl2 = 0.10206207261596575f * 1.4426950408889634f;

    bf16x8 bq[2][3];
#pragma unroll
    for (int qt = 0; qt < 2; ++qt)
#pragma unroll
        for (int kd = 0; kd < 3; ++kd)
            bq[qt][kd] = *(const bf16x8*)(qkv + (size_t)(srow0 + qt * 16 + lrow) * QKVN +
                                          qh * 96 + kd * 32 + lhi * 8);

    float m_s[2] = {-3e38f, -3e38f}, l_s[2] = {0.0f, 0.0f};
    f32x4 oacc[6][2] = {};

    const int s0 = lrow + ((lane & 16) ? 32 : 0);
    const int s1 = s0 + 16;
    const bool khi = (lane & 32) != 0;

    const size_t kvrow0 = (size_t)(bb * S_LEN) * QKVN;
    u16x8 kreg[3], vreg[3];

    {
        const size_t kbase = kvrow0 + KOFF + (size_t)kvh * 96;
        const size_t vbase = kvrow0 + VOFF + (size_t)kvh * 96;
#pragma unroll
        for (int i = 0; i < 3; ++i) {
            const int u = tid + 256 * i;
            const int so = (u % 12) * 8, sr = u / 12;
            kreg[i] = *(const u16x8*)(qkv + kbase + (size_t)sr * QKVN + so);
            vreg[i] = *(const u16x8*)(qkv + vbase + (size_t)sr * QKVN + so);
        }
#pragma unroll
        for (int i = 0; i < 3; ++i) {
            const int u = tid + 256 * i;
            const int so = (u % 12) * 8, sr = u / 12;
            *(u16x8*)(Ks + sr * KSP + so) = kreg[i];
            *(u16x8*)(Vtmp + sr * 96 + so) = vreg[i];
        }
        __syncthreads();
#pragma unroll
        for (int i = 0; i < 3; ++i) {
            const int u = tid + 256 * i;
            const int td = u % 96, ts8 = u / 96;
            u16x8 c;
#pragma unroll
            for (int j = 0; j < 8; ++j) c[j] = Vtmp[(ts8 * 8 + j) * 96 + td];
            *(u16x8*)(Vt + td * 72 + ts8 * 8) = c;
        }
    }

    for (int kb = 0; kb <= kb_last; ++kb) {
        if (kb < kb_last) {
            const size_t kbase2 = kvrow0 + (size_t)((kb + 1) * 64) * QKVN + KOFF + kvh * 96;
            const size_t vbase2 = kvrow0 + (size_t)((kb + 1) * 64) * QKVN + VOFF + kvh * 96;
#pragma unroll
            for (int i = 0; i < 3; ++i) {
                const int u = tid + 256 * i;
                const int so = (u % 12) * 8, sr = u / 12;
                kreg[i] = *(const u16x8*)(qkv + kbase2 + (size_t)sr * QKVN + so);
                vreg[i] = *(const u16x8*)(qkv + vbase2 + (size_t)sr * QKVN + so);
            }
        }
        __syncthreads();

        bf16x8 ka[4][3];
#pragma unroll
        for (int kt = 0; kt < 4; ++kt)
#pragma unroll
            for (int kd = 0; kd < 3; ++kd)
                ka[kt][kd] = *(const bf16x8*)(Ks + (kt * 16 + lrow) * KSP + kd * 32 + lhi * 8);

        const int qoff = qt32 * 32 - kb * 64;
        const bool lastkb = (kb == kb_last);
        u32 bp[2][2][4];

#pragma unroll
        for (int qt = 0; qt < 2; ++qt) {
            const int qrelmax = qoff + qt * 16 + 15;
            f32x4 sacc[4] = {};
#pragma unroll
            for (int kt = 0; kt < 4; ++kt) {
                if (lastkb && kt * 16 > qrelmax) continue;
#pragma unroll
                for (int kd = 0; kd < 3; ++kd)
                    sacc[kt] = __builtin_amdgcn_mfma_f32_16x16x32_bf16(ka[kt][kd], bq[qt][kd],
                                                                       sacc[kt], 0, 0, 0);
            }
            float p[4][4];
            float mx = -3e38f;
            if (lastkb) {
                const int qrel = qoff + qt * 16 + lrow;
#pragma unroll
                for (int kt = 0; kt < 4; ++kt)
#pragma unroll
                    for (int r = 0; r < 4; ++r) {
                        const bool live = (kt * 16 + lhi * 4 + r) <= qrel;
                        const float s = live ? sacc[kt][r] : -3e38f;
                        p[kt][r] = s;
                        mx = fmaxf(mx, s);
                    }
            } else {
#pragma unroll
                for (int kt = 0; kt < 4; ++kt)
#pragma unroll
                    for (int r = 0; r < 4; ++r) {
                        p[kt][r] = sacc[kt][r];
                        mx = fmaxf(mx, sacc[kt][r]);
                    }
            }
            mx = fmaxf(mx, __shfl_xor(mx, 16));
            mx = fmaxf(mx, __shfl_xor(mx, 32));
            float mn = m_s[qt];
            if (!__all(mx - mn <= 20.0f)) {
                const float mnew = fmaxf(mn, mx);
                const float alpha = exp2f((mn - mnew) * cl2);
                m_s[qt] = mnew;
                mn = mnew;
                l_s[qt] *= alpha;
#pragma unroll
                for (int dt = 0; dt < 6; ++dt)
#pragma unroll
                    for (int r = 0; r < 4; ++r) oacc[dt][qt][r] *= alpha;
            }
            float rs = 0.0f;
#pragma unroll
            for (int kt = 0; kt < 4; ++kt)
#pragma unroll
                for (int r = 0; r < 4; ++r) {
                    const float pv = exp2f((p[kt][r] - mn) * cl2);
                    p[kt][r] = pv;
                    rs += pv;
                }
            rs += __shfl_xor(rs, 16);
            rs += __shfl_xor(rs, 32);
            l_s[qt] += rs;
            u32 pk[4][2];
#pragma unroll
            for (int kt = 0; kt < 4; ++kt) {
                pk[kt][0] = cvtpk(p[kt][0], p[kt][1]);
                pk[kt][1] = cvtpk(p[kt][2], p[kt][3]);
            }
#pragma unroll
            for (int kk = 0; kk < 2; ++kk) {
                const u32 a0 = (u32)__shfl((int)pk[kk * 2][0], s0, 64);
                const u32 b0 = (u32)__shfl((int)pk[kk * 2 + 1][0], s0, 64);
                const u32 a1 = (u32)__shfl((int)pk[kk * 2][1], s0, 64);
                const u32 b1 = (u32)__shfl((int)pk[kk * 2 + 1][1], s0, 64);
                const u32 a2 = (u32)__shfl((int)pk[kk * 2][0], s1, 64);
                const u32 b2 = (u32)__shfl((int)pk[kk * 2 + 1][0], s1, 64);
                const u32 a3 = (u32)__shfl((int)pk[kk * 2][1], s1, 64);
                const u32 b3 = (u32)__shfl((int)pk[kk * 2 + 1][1], s1, 64);
                bp[qt][kk][0] = khi ? b0 : a0;
                bp[qt][kk][1] = khi ? b1 : a1;
                bp[qt][kk][2] = khi ? b2 : a2;
                bp[qt][kk][3] = khi ? b3 : a3;
            }
        }

#pragma unroll
        for (int dt = 0; dt < 6; ++dt) {
            bf16x8 va[2];
#pragma unroll
            for (int kk = 0; kk < 2; ++kk)
                va[kk] = *(const bf16x8*)(Vt + (dt * 16 + lrow) * 72 + kk * 32 + lhi * 8);
#pragma unroll
            for (int qt = 0; qt < 2; ++qt)
#pragma unroll
                for (int kk = 0; kk < 2; ++kk) {
                    const u32x4 bv = {bp[qt][kk][0], bp[qt][kk][1], bp[qt][kk][2], bp[qt][kk][3]};
                    oacc[dt][qt] = __builtin_amdgcn_mfma_f32_16x16x32_bf16(
                        va[kk], __builtin_bit_cast(bf16x8, bv), oacc[dt][qt], 0, 0, 0);
                }
        }

        __syncthreads();
        if (kb < kb_last) {
#pragma unroll
            for (int i = 0; i < 3; ++i) {
                const int u = tid + 256 * i;
                const int so = (u % 12) * 8, sr = u / 12;
                *(u16x8*)(Ks + sr * KSP + so) = kreg[i];
                *(u16x8*)(Vtmp + sr * 96 + so) = vreg[i];
            }
            __syncthreads();
#pragma unroll
            for (int i = 0; i < 3; ++i) {
                const int u = tid + 256 * i;
                const int td = u % 96, ts8 = u / 96;
                u16x8 c;
#pragma unroll
                for (int j = 0; j < 8; ++j) c[j] = Vtmp[(ts8 * 8 + j) * 96 + td];
                *(u16x8*)(Vt + td * 72 + ts8 * 8) = c;
            }
        }
    }

    const size_t obase = (size_t)srow0 * EMB + qh * 96;
#pragma unroll
    for (int qt = 0; qt < 2; ++qt) {
        const float inv = 1.0f / l_s[qt];
        const size_t rbase = obase + (size_t)(qt * 16 + lrow) * EMB;
#pragma unroll
        for (int dt = 0; dt < 6; ++dt)
#pragma unroll
            for (int rp = 0; rp < 2; ++rp) {
                const u32 pair = cvtpk(oacc[dt][qt][2 * rp] * inv, oacc[dt][qt][2 * rp + 1] * inv);
                *(u32*)(out + rbase + dt * 16 + lhi * 4 + 2 * rp) = pair;
            }
    }
}

extern "C" void kernel_launch(void* const* d_in, const int* in_sizes, int n_in,
                              void* d_out, int out_size, void* d_ws, size_t ws_size,
                              hipStream_t stream) {
    const float* x = (const float*)d_in[0];
    const int* positions = (const int*)d_in[1];
    const float* W_qkv = (const float*)d_in[3];
    const float* W_o = (const float*)d_in[4];
    float* out = (float*)d_out;

    const int M = BATCH * S_LEN;               // 4096
    const size_t QKV_E = (size_t)M * QKVN;     // 18,874,368
    const size_t X_E = (size_t)M * EMB;
    const size_t WQKV_E = (size_t)QKVN * EMB;  // 28.3 MB bf16
    const size_t WO_E = (size_t)EMB * EMB;

    // ws (62.9 MB): qkv [0,QKV_E) ; scratch [QKV_E, +ATT_E) = xb -> attn_out
    // d_out (50.3 MB): wqkvb (dead after GEMM1)
    u16* qkv = (u16*)d_ws;
    u16* scratch = qkv + QKV_E;
    u16* xb = scratch;
    u16* wqkvb = (u16*)d_out;
    u16* wob = (u16*)d_ws;  // overwrites qkv head after attn

    conv_f2b<<<(int)(X_E / 8 / 256), 256, 0, stream>>>(x, xb, (int)(X_E / 8));
    conv_f2b<<<(int)(WQKV_E / 8 / 256), 256, 0, stream>>>(W_qkv, wqkvb, (int)(WQKV_E / 8));
    gemm_bt8<false>
        <<<dim3(QKVN / 256, M / 256), 512, 0, stream>>>(xb, wqkvb, qkv, M, QKVN, EMB, QKVN);
    gqa_rope8<<<(BATCH * S_LEN * (NQH + NKVH) * 6) / 256, 256, 0, stream>>>(qkv, positions);
    gqa_attn5<<<dim3(1024), 256, 0, stream>>>(qkv, scratch);  // overwrites xb (dead)
    conv_f2b<<<(int)(WO_E / 8 / 256), 256, 0, stream>>>(W_o, wob, (int)(WO_E / 8));
    gemm_bt8<true>
        <<<dim3(EMB / 256, M / 256), 512, 0, stream>>>(scratch, wob, out, M, EMB, EMB, EMB);
}

// Round 7
// 597.327 us; speedup vs baseline: 1.0735x; 1.0735x over previous
//
#include <hip/hip_runtime.h>
#include <cstdint>

typedef unsigned short u16;
typedef unsigned int u32;
typedef __attribute__((ext_vector_type(4))) float f32x4;
typedef __attribute__((ext_vector_type(8))) __bf16 bf16x8;
typedef __attribute__((ext_vector_type(8))) unsigned short u16x8;
typedef __attribute__((ext_vector_type(4))) unsigned int u32x4;

#define S_LEN 2048
#define BATCH 2
#define NQH 32
#define NKVH 8
#define HD 96
#define EMB 3072
#define QKVN 4608
#define KOFF 3072
#define VOFF 3840
#define KSP 104

__device__ __forceinline__ u16 f2b(float f) {
    u32 u = __float_as_uint(f);
    u32 r = (u + 0x7fffu + ((u >> 16) & 1u)) >> 16;
    return (u16)r;
}
__device__ __forceinline__ float b2f(u16 h) { return __uint_as_float(((u32)h) << 16); }
__device__ __forceinline__ u32 cvtpk(float lo, float hi) {
    u32 r;
    asm("v_cvt_pk_bf16_f32 %0, %1, %2" : "=v"(r) : "v"(lo), "v"(hi));
    return r;
}

// ---------------- fp32 -> bf16 bulk convert ----------------
__global__ __launch_bounds__(256) void conv_f2b(const float* __restrict__ in,
                                                u16* __restrict__ outp, int n8) {
    const int i = blockIdx.x * 256 + threadIdx.x;
    if (i >= n8) return;
    const f32x4* q = (const f32x4*)(in + (size_t)i * 8);
    const f32x4 a = q[0], b = q[1];
    u16x8 t;
#pragma unroll
    for (int j = 0; j < 4; ++j) {
        t[j] = f2b(a[j]);
        t[j + 4] = f2b(b[j]);
    }
    *(u16x8*)(outp + (size_t)i * 8) = t;
}

// ---------------- async global->LDS helper ----------------
typedef __attribute__((address_space(1))) const uint32_t gas_u32;
typedef __attribute__((address_space(3))) uint32_t las_u32;
__device__ __forceinline__ void gld_lds16(const u16* g, u16* l) {
    __builtin_amdgcn_global_load_lds((gas_u32*)g, (las_u32*)l, 16, 0, 0);
}

#define WAITV8 asm volatile("s_waitcnt vmcnt(8)" ::: "memory")
#define LGKM0 asm volatile("s_waitcnt lgkmcnt(0)" ::: "memory")
// asm barrier WITH memory clobber: compiler fence + HW barrier (builtin is not a fence)
#define BARRIERM asm volatile("s_barrier" ::: "memory")
#define SCHEDB __builtin_amdgcn_sched_barrier(0)

// ============ 256x256 GEMM, BK=32, 4-deep LDS ring, 1 barrier/tile ============
// C[M,N] = A[M,K]*B[N,K]^T. 512 thr = 8 waves (2M x 4N). LDS: 4 bufs x (A 16KB + B 16KB).
// Tile t staged during tile t-3 -> vmcnt(8) at tile top waits loads issued ~6 phases ago.
// Swizzle (64B rows, 4 slots of 16B): slot ^= (row>>1)&3; applied to GLOBAL source col
// (gld_lds writes linear) and to ds_read addr (same involution; 2-way banks = free).
__device__ __forceinline__ void stage32(const u16* __restrict__ G, int ldg, int k0,
                                        u16* buf, int tid) {
#pragma unroll
    for (int L = 0; L < 2; ++L) {
        const int c = L * 512 + tid;   // 16B chunk id: row r = c>>2, slot = c&3
        const int r = c >> 2;
        const int sg = (c & 3) ^ ((r >> 1) & 3);
        const u16* src = G + (size_t)r * ldg + k0 + sg * 8;
        u16* dst = buf + (L * 512 + (tid & 448)) * 8;  // wave-uniform base; lane*16B by HW
        gld_lds16(src, dst);
    }
}

__device__ __forceinline__ bf16x8 frag32(const u16* buf, int row, int s) {
    const int sg = s ^ ((row >> 1) & 3);
    return *(const bf16x8*)(buf + row * 32 + sg * 8);
}

template <bool OUTF32>
__global__ __launch_bounds__(512, 1) void gemm_bt32(const u16* __restrict__ Ap,
                                                    const u16* __restrict__ Bp,
                                                    void* __restrict__ Cp,
                                                    int M, int N, int K, int ldc) {
    __shared__ __align__(16) u16 S[65536];  // 128 KB: buf b at S+b*16384 (A), +8192 (B)
    const int tid = threadIdx.x;
    const int lane = tid & 63;
    const int lrow = lane & 15, lhi = lane >> 4;
    const int wid = tid >> 6;
    const int wr = wid >> 2, wc = wid & 3;
    const int bm = blockIdx.y * 256, bn = blockIdx.x * 256;
    const u16* Ab = Ap + (size_t)bm * K;
    const u16* Bb = Bp + (size_t)bn * K;

    f32x4 acc[8][4] = {};
    const int nt = K >> 5;  // 96
    const int arow0 = wr * 128 + lrow;
    const int brow0 = wc * 64 + lrow;

    // prologue: stage tiles 0,1,2 (12 loads in flight per thread)
#pragma unroll
    for (int t = 0; t < 3; ++t) {
        stage32(Ab, K, t * 32, S + t * 16384, tid);
        stage32(Bb, K, t * 32, S + t * 16384 + 8192, tid);
    }

    for (int t = 0; t < nt; ++t) {
        const u16* Ac = S + (t & 3) * 16384;
        const u16* Bc = Ac + 8192;
        u16* Sn = S + ((t + 3) & 3) * 16384;
        const int kn = (t + 3 < nt) ? (t + 3) * 32 : 0;  // clamp: dummy loads keep vmcnt uniform

        WAITV8;    // my 4 oldest loads (= tile t, staged 3 tiles ago) landed
        BARRIERM;  // all waves' tile-t loads landed; all tile t-1 reads of Sn done

        // ---- phase 1: quadrant ni0-1; stage A(t+3) ----
        bf16x8 af[8], bfr[2];
#pragma unroll
        for (int mi = 0; mi < 8; ++mi) af[mi] = frag32(Ac, arow0 + mi * 16, lhi);
#pragma unroll
        for (int ni = 0; ni < 2; ++ni) bfr[ni] = frag32(Bc, brow0 + ni * 16, lhi);
        stage32(Ab, K, kn, Sn, tid);
        LGKM0;
        SCHEDB;
        __builtin_amdgcn_s_setprio(1);
#pragma unroll
        for (int mi = 0; mi < 8; ++mi)
#pragma unroll
            for (int ni = 0; ni < 2; ++ni)
                acc[mi][ni] = __builtin_amdgcn_mfma_f32_16x16x32_bf16(af[mi], bfr[ni],
                                                                      acc[mi][ni], 0, 0, 0);
        __builtin_amdgcn_s_setprio(0);

        // ---- phase 2: quadrant ni2-3; stage B(t+3) ----
#pragma unroll
        for (int ni = 0; ni < 2; ++ni) bfr[ni] = frag32(Bc, brow0 + (ni + 2) * 16, lhi);
        stage32(Bb, K, kn, Sn + 8192, tid);
        LGKM0;
        SCHEDB;
        __builtin_amdgcn_s_setprio(1);
#pragma unroll
        for (int mi = 0; mi < 8; ++mi)
#pragma unroll
            for (int ni = 0; ni < 2; ++ni)
                acc[mi][ni + 2] = __builtin_amdgcn_mfma_f32_16x16x32_bf16(af[mi], bfr[ni],
                                                                          acc[mi][ni + 2], 0, 0, 0);
        __builtin_amdgcn_s_setprio(0);
    }

    // epilogue: C/D layout col=lane&15, row=(lane>>4)*4+reg (verified mapping, R6 refcheck)
    const int orow = bm + wr * 128 + lhi * 4;
    const int ocol = bn + wc * 64 + lrow;
#pragma unroll
    for (int mi = 0; mi < 8; ++mi)
#pragma unroll
        for (int ni = 0; ni < 4; ++ni)
#pragma unroll
            for (int r = 0; r < 4; ++r) {
                const size_t idx = (size_t)(orow + mi * 16 + r) * ldc + ocol + ni * 16;
                if constexpr (OUTF32)
                    ((float*)Cp)[idx] = acc[mi][ni][r];
                else
                    ((u16*)Cp)[idx] = f2b(acc[mi][ni][r]);
            }
}

// ---------------- RoPE in-place, vectorized: 8 pairs per thread ----------------
__global__ __launch_bounds__(256) void gqa_rope8(u16* __restrict__ qkv,
                                                 const int* __restrict__ positions) {
    const int i = blockIdx.x * 256 + threadIdx.x;
    const int pc = i % 6;
    int t = i / 6;
    const int head = t % (NQH + NKVH);
    const int bs = t / (NQH + NKVH);
    const int pos = positions[bs & (S_LEN - 1)];
    const size_t base = (size_t)bs * QKVN +
                        (head < NQH ? head * HD : KOFF + (head - NQH) * HD) + pc * 8;
    const u16x8 a = *(const u16x8*)(qkv + base);
    const u16x8 b = *(const u16x8*)(qkv + base + 48);
    u16x8 ra, rb;
#pragma unroll
    for (int jj = 0; jj < 8; ++jj) {
        const int pair = pc * 8 + jj;
        const float invf = __expf(-(float)(2 * pair) * (1.0f / 96.0f) * 9.210340371976184f);
        const float ang = (float)pos * invf;
        float sn, cs;
        __sincosf(ang, &sn, &cs);
        const float t1 = b2f(a[jj]), t2 = b2f(b[jj]);
        ra[jj] = f2b(t1 * cs - t2 * sn);
        rb[jj] = f2b(t2 * cs + t1 * sn);
    }
    *(u16x8*)(qkv + base) = ra;
    *(u16x8*)(qkv + base + 48) = rb;
}

// ---------------- Flash GQA v5 (unchanged) ----------------
__global__ __launch_bounds__(256) void gqa_attn5(const u16* __restrict__ qkv,
                                                 u16* __restrict__ out) {
    __shared__ __align__(16) u16 Ks[64 * KSP];
    __shared__ __align__(16) u16 Vtmp[64 * 96];
    __shared__ __align__(16) u16 Vt[96 * 72];

    const int tid = threadIdx.x;
    const int wave = tid >> 6, lane = tid & 63;
    const int lrow = lane & 15, lhi = lane >> 4;
    const int bx = blockIdx.x;
    const int qt32 = 63 - (bx >> 4);
    const int kvh = (bx >> 1) & 7, bb = bx & 1;
    const int qh = kvh * 4 + wave;
    const int srow0 = bb * S_LEN + qt32 * 32;
    const int kb_last = (qt32 * 32 + 31) >> 6;
    const float cl2 = 0.10206207261596575f * 1.4426950408889634f;

    bf16x8 bq[2][3];
#pragma unroll
    for (int qt = 0; qt < 2; ++qt)
#pragma unroll
        for (int kd = 0; kd < 3; ++kd)
            bq[qt][kd] = *(const bf16x8*)(qkv + (size_t)(srow0 + qt * 16 + lrow) * QKVN +
                                          qh * 96 + kd * 32 + lhi * 8);

    float m_s[2] = {-3e38f, -3e38f}, l_s[2] = {0.0f, 0.0f};
    f32x4 oacc[6][2] = {};

    const int s0 = lrow + ((lane & 16) ? 32 : 0);
    const int s1 = s0 + 16;
    const bool khi = (lane & 32) != 0;

    const size_t kvrow0 = (size_t)(bb * S_LEN) * QKVN;
    u16x8 kreg[3], vreg[3];

    {
        const size_t kbase = kvrow0 + KOFF + (size_t)kvh * 96;
        const size_t vbase = kvrow0 + VOFF + (size_t)kvh * 96;
#pragma unroll
        for (int i = 0; i < 3; ++i) {
            const int u = tid + 256 * i;
            const int so = (u % 12) * 8, sr = u / 12;
            kreg[i] = *(const u16x8*)(qkv + kbase + (size_t)sr * QKVN + so);
            vreg[i] = *(const u16x8*)(qkv + vbase + (size_t)sr * QKVN + so);
        }
#pragma unroll
        for (int i = 0; i < 3; ++i) {
            const int u = tid + 256 * i;
            const int so = (u % 12) * 8, sr = u / 12;
            *(u16x8*)(Ks + sr * KSP + so) = kreg[i];
            *(u16x8*)(Vtmp + sr * 96 + so) = vreg[i];
        }
        __syncthreads();
#pragma unroll
        for (int i = 0; i < 3; ++i) {
            const int u = tid + 256 * i;
            const int td = u % 96, ts8 = u / 96;
            u16x8 c;
#pragma unroll
            for (int j = 0; j < 8; ++j) c[j] = Vtmp[(ts8 * 8 + j) * 96 + td];
            *(u16x8*)(Vt + td * 72 + ts8 * 8) = c;
        }
    }

    for (int kb = 0; kb <= kb_last; ++kb) {
        if (kb < kb_last) {
            const size_t kbase2 = kvrow0 + (size_t)((kb + 1) * 64) * QKVN + KOFF + kvh * 96;
            const size_t vbase2 = kvrow0 + (size_t)((kb + 1) * 64) * QKVN + VOFF + kvh * 96;
#pragma unroll
            for (int i = 0; i < 3; ++i) {
                const int u = tid + 256 * i;
                const int so = (u % 12) * 8, sr = u / 12;
                kreg[i] = *(const u16x8*)(qkv + kbase2 + (size_t)sr * QKVN + so);
                vreg[i] = *(const u16x8*)(qkv + vbase2 + (size_t)sr * QKVN + so);
            }
        }
        __syncthreads();

        bf16x8 ka[4][3];
#pragma unroll
        for (int kt = 0; kt < 4; ++kt)
#pragma unroll
            for (int kd = 0; kd < 3; ++kd)
                ka[kt][kd] = *(const bf16x8*)(Ks + (kt * 16 + lrow) * KSP + kd * 32 + lhi * 8);

        const int qoff = qt32 * 32 - kb * 64;
        const bool lastkb = (kb == kb_last);
        u32 bp[2][2][4];

#pragma unroll
        for (int qt = 0; qt < 2; ++qt) {
            const int qrelmax = qoff + qt * 16 + 15;
            f32x4 sacc[4] = {};
#pragma unroll
            for (int kt = 0; kt < 4; ++kt) {
                if (lastkb && kt * 16 > qrelmax) continue;
#pragma unroll
                for (int kd = 0; kd < 3; ++kd)
                    sacc[kt] = __builtin_amdgcn_mfma_f32_16x16x32_bf16(ka[kt][kd], bq[qt][kd],
                                                                       sacc[kt], 0, 0, 0);
            }
            float p[4][4];
            float mx = -3e38f;
            if (lastkb) {
                const int qrel = qoff + qt * 16 + lrow;
#pragma unroll
                for (int kt = 0; kt < 4; ++kt)
#pragma unroll
                    for (int r = 0; r < 4; ++r) {
                        const bool live = (kt * 16 + lhi * 4 + r) <= qrel;
                        const float s = live ? sacc[kt][r] : -3e38f;
                        p[kt][r] = s;
                        mx = fmaxf(mx, s);
                    }
            } else {
#pragma unroll
                for (int kt = 0; kt < 4; ++kt)
#pragma unroll
                    for (int r = 0; r < 4; ++r) {
                        p[kt][r] = sacc[kt][r];
                        mx = fmaxf(mx, sacc[kt][r]);
                    }
            }
            mx = fmaxf(mx, __shfl_xor(mx, 16));
            mx = fmaxf(mx, __shfl_xor(mx, 32));
            float mn = m_s[qt];
            if (!__all(mx - mn <= 20.0f)) {
                const float mnew = fmaxf(mn, mx);
                const float alpha = exp2f((mn - mnew) * cl2);
                m_s[qt] = mnew;
                mn = mnew;
                l_s[qt] *= alpha;
#pragma unroll
                for (int dt = 0; dt < 6; ++dt)
#pragma unroll
                    for (int r = 0; r < 4; ++r) oacc[dt][qt][r] *= alpha;
            }
            float rs = 0.0f;
#pragma unroll
            for (int kt = 0; kt < 4; ++kt)
#pragma unroll
                for (int r = 0; r < 4; ++r) {
                    const float pv = exp2f((p[kt][r] - mn) * cl2);
                    p[kt][r] = pv;
                    rs += pv;
                }
            rs += __shfl_xor(rs, 16);
            rs += __shfl_xor(rs, 32);
            l_s[qt] += rs;
            u32 pk[4][2];
#pragma unroll
            for (int kt = 0; kt < 4; ++kt) {
                pk[kt][0] = cvtpk(p[kt][0], p[kt][1]);
                pk[kt][1] = cvtpk(p[kt][2], p[kt][3]);
            }
#pragma unroll
            for (int kk = 0; kk < 2; ++kk) {
                const u32 a0 = (u32)__shfl((int)pk[kk * 2][0], s0, 64);
                const u32 b0 = (u32)__shfl((int)pk[kk * 2 + 1][0], s0, 64);
                const u32 a1 = (u32)__shfl((int)pk[kk * 2][1], s0, 64);
                const u32 b1 = (u32)__shfl((int)pk[kk * 2 + 1][1], s0, 64);
                const u32 a2 = (u32)__shfl((int)pk[kk * 2][0], s1, 64);
                const u32 b2 = (u32)__shfl((int)pk[kk * 2 + 1][0], s1, 64);
                const u32 a3 = (u32)__shfl((int)pk[kk * 2][1], s1, 64);
                const u32 b3 = (u32)__shfl((int)pk[kk * 2 + 1][1], s1, 64);
                bp[qt][kk][0] = khi ? b0 : a0;
                bp[qt][kk][1] = khi ? b1 : a1;
                bp[qt][kk][2] = khi ? b2 : a2;
                bp[qt][kk][3] = khi ? b3 : a3;
            }
        }

#pragma unroll
        for (int dt = 0; dt < 6; ++dt) {
            bf16x8 va[2];
#pragma unroll
            for (int kk = 0; kk < 2; ++kk)
                va[kk] = *(const bf16x8*)(Vt + (dt * 16 + lrow) * 72 + kk * 32 + lhi * 8);
#pragma unroll
            for (int qt = 0; qt < 2; ++qt)
#pragma unroll
                for (int kk = 0; kk < 2; ++kk) {
                    const u32x4 bv = {bp[qt][kk][0], bp[qt][kk][1], bp[qt][kk][2], bp[qt][kk][3]};
                    oacc[dt][qt] = __builtin_amdgcn_mfma_f32_16x16x32_bf16(
                        va[kk], __builtin_bit_cast(bf16x8, bv), oacc[dt][qt], 0, 0, 0);
                }
        }

        __syncthreads();
        if (kb < kb_last) {
#pragma unroll
            for (int i = 0; i < 3; ++i) {
                const int u = tid + 256 * i;
                const int so = (u % 12) * 8, sr = u / 12;
                *(u16x8*)(Ks + sr * KSP + so) = kreg[i];
                *(u16x8*)(Vtmp + sr * 96 + so) = vreg[i];
            }
            __syncthreads();
#pragma unroll
            for (int i = 0; i < 3; ++i) {
                const int u = tid + 256 * i;
                const int td = u % 96, ts8 = u / 96;
                u16x8 c;
#pragma unroll
                for (int j = 0; j < 8; ++j) c[j] = Vtmp[(ts8 * 8 + j) * 96 + td];
                *(u16x8*)(Vt + td * 72 + ts8 * 8) = c;
            }
        }
    }

    const size_t obase = (size_t)srow0 * EMB + qh * 96;
#pragma unroll
    for (int qt = 0; qt < 2; ++qt) {
        const float inv = 1.0f / l_s[qt];
        const size_t rbase = obase + (size_t)(qt * 16 + lrow) * EMB;
#pragma unroll
        for (int dt = 0; dt < 6; ++dt)
#pragma unroll
            for (int rp = 0; rp < 2; ++rp) {
                const u32 pair = cvtpk(oacc[dt][qt][2 * rp] * inv, oacc[dt][qt][2 * rp + 1] * inv);
                *(u32*)(out + rbase + dt * 16 + lhi * 4 + 2 * rp) = pair;
            }
    }
}

extern "C" void kernel_launch(void* const* d_in, const int* in_sizes, int n_in,
                              void* d_out, int out_size, void* d_ws, size_t ws_size,
                              hipStream_t stream) {
    const float* x = (const float*)d_in[0];
    const int* positions = (const int*)d_in[1];
    const float* W_qkv = (const float*)d_in[3];
    const float* W_o = (const float*)d_in[4];
    float* out = (float*)d_out;

    const int M = BATCH * S_LEN;               // 4096
    const size_t QKV_E = (size_t)M * QKVN;     // 18,874,368
    const size_t X_E = (size_t)M * EMB;
    const size_t WQKV_E = (size_t)QKVN * EMB;  // 28.3 MB bf16
    const size_t WO_E = (size_t)EMB * EMB;

    // ws (62.9 MB): qkv [0,QKV_E) ; scratch [QKV_E, +ATT_E) = xb -> attn_out
    // d_out (50.3 MB): wqkvb (dead after GEMM1)
    u16* qkv = (u16*)d_ws;
    u16* scratch = qkv + QKV_E;
    u16* xb = scratch;
    u16* wqkvb = (u16*)d_out;
    u16* wob = (u16*)d_ws;  // overwrites qkv head after attn

    conv_f2b<<<(int)(X_E / 8 / 256), 256, 0, stream>>>(x, xb, (int)(X_E / 8));
    conv_f2b<<<(int)(WQKV_E / 8 / 256), 256, 0, stream>>>(W_qkv, wqkvb, (int)(WQKV_E / 8));
    gemm_bt32<false>
        <<<dim3(QKVN / 256, M / 256), 512, 0, stream>>>(xb, wqkvb, qkv, M, QKVN, EMB, QKVN);
    gqa_rope8<<<(BATCH * S_LEN * (NQH + NKVH) * 6) / 256, 256, 0, stream>>>(qkv, positions);
    gqa_attn5<<<dim3(1024), 256, 0, stream>>>(qkv, scratch);  // overwrites xb (dead)
    conv_f2b<<<(int)(WO_E / 8 / 256), 256, 0, stream>>>(W_o, wob, (int)(WO_E / 8));
    gemm_bt32<true>
        <<<dim3(EMB / 256, M / 256), 512, 0, stream>>>(scratch, wob, out, M, EMB, EMB, EMB);
}